// Round 3
// 527.997 us; speedup vs baseline: 1.2275x; 1.2275x over previous
//
#include <hip/hip_runtime.h>
#include <hip/hip_bf16.h>
#include <stdint.h>

// Problem constants (fixed by the reference)
#define NUM_RANKS 8
#define M_DIM 8192   // global token dim
#define N_DIM 4096   // output features
#define K_LOC 512    // per-rank K shard
#define K_DIM 4096   // NUM_RANKS * K_LOC — effective GEMM K
#define NT    (K_DIM / 64)   // 64 K-tiles of BK=64

typedef __bf16 bf16x8 __attribute__((ext_vector_type(8)));
typedef float f32x4 __attribute__((ext_vector_type(4)));

// RNE float->bf16 (inputs are finite gaussians)
__device__ __forceinline__ uint32_t f2bf(float f) {
    union { float f; uint32_t u; } cv;
    cv.f = f;
    uint32_t x = cv.u;
    return ((x + 0x7fffu + ((x >> 16) & 1u)) >> 16) & 0xffffu;
}

// Fused convert + relayout for both operands in ONE launch (grid-stride).
//   a[src][row][k] fp32 -> Abf[row][src*512+k] bf16   (rowShift=13)
//   b[src][row][k] fp32 -> Bbf[row][src*512+k] bf16   (rowShift=12)
__global__ __launch_bounds__(256) void cvt_fused(
    const float* __restrict__ a, const float* __restrict__ b,
    unsigned short* __restrict__ Abf, unsigned short* __restrict__ Bbf)
{
    const long ACH = (long)NUM_RANKS * M_DIM * (K_LOC / 8);          // 4194304 chunks
    const long TCH = ACH + (long)NUM_RANKS * N_DIM * (K_LOC / 8);    // +2097152
    for (long c = (long)blockIdx.x * 256 + threadIdx.x; c < TCH;
         c += (long)gridDim.x * 256) {
        const float* in; unsigned short* out; long e; int rowShift;
        if (c < ACH) { in = a; out = Abf; e = c << 3;        rowShift = 13; }
        else         { in = b; out = Bbf; e = (c - ACH) << 3; rowShift = 12; }
        const int src = (int)(e >> (rowShift + 9));
        const int row = (int)((e >> 9) & ((1 << rowShift) - 1));
        const int k   = (int)(e & 511);
        const float4 f0 = *(const float4*)(in + e);
        const float4 f1 = *(const float4*)(in + e + 4);
        uint4 v;
        v.x = f2bf(f0.x) | (f2bf(f0.y) << 16);
        v.y = f2bf(f0.z) | (f2bf(f0.w) << 16);
        v.z = f2bf(f1.x) | (f2bf(f1.y) << 16);
        v.w = f2bf(f1.z) | (f2bf(f1.w) << 16);
        *(uint4*)(out + ((long)row << 12) + (src << 9) + k) = v;
    }
}

// 16B direct global->LDS DMA. LDS dst: wave-uniform base + lane*16.
// Global src is per-lane => swizzle realized by inverse-swizzling the SOURCE
// column; LDS stays linear (both-sides-or-neither rule).
__device__ __forceinline__ void load_lds16(const void* g, void* l) {
    __builtin_amdgcn_global_load_lds(
        (__attribute__((address_space(1))) void*)g,
        (__attribute__((address_space(3))) void*)l,
        16, 0, 0);
}

// ============================================================================
// 256x256 8-phase GEMM, C[M][N] = A[M][K] * B[N][K]^T, bf16 in, fp32 out.
// 512 thr = 8 waves (2M x 4N), per-wave 128x64 out, BK=64, 128 KiB LDS dbuf.
//
// LDS swizzle: row r's logical 16B chunk c stored at physical chunk c^(r&7).
// Writer thread t covers phys chunks t, t+512 of each 128-row half-region with
// pre-inverse-swizzled global source column cs. Reader fragment (row base+l16,
// logical chunk ks*4+quad) reads phys (ks*4+quad)^(l16&7): 8 lanes per 4-bank
// group = bandwidth-minimum service, conflict-free.
//
// Staging discipline (R2 fix — the R1 bug was staging tile t+2 into the
// CURRENT buffer at ph2/ph3, clobbering rows that waves still read at ph3/ph4;
// wave wm/wn reads its OWN half in ph1 AND ph3/ph4, so in-tile regions are
// never overwrite-safe until their last-read phase has barrier-drained):
//   During tile t (buf b = t&1), buf b^1 is idle -> stage ALL of tile t+1
//   into b^1:  A1(t+1)@ph1, B0(t+1)@ph2, B1(t+1)@ph3.
//   The only same-buffer stage is A0(t+2)@ph4: both A-halves of buf b are
//   fully read + barrier-drained by end of ph3.  Issue->consume distances:
//   A0 4.5 phases, A1 3.5, B0 2.5, B1 1.5 (A streams HBM -> longest).
//   End-of-tile s_waitcnt vmcnt(2) (= the 2 A0(t+2) loads outstanding)
//   proves tile t+1 fully resident before its ph1 ds_reads. Counted, never 0
//   in steady state (T4). Tail: tile NT-2 drains vmcnt(0), NT-1 stages nothing.
//
// All barriers are asm("s_barrier") with "memory" clobber + sched_barrier(0)
// so no ds_read/DMA can be moved across a phase boundary by the scheduler.
// ============================================================================

#define MFMA16 __builtin_amdgcn_mfma_f32_16x16x32_bf16
#define BAR() do { \
    __builtin_amdgcn_sched_barrier(0); \
    asm volatile("s_barrier" ::: "memory"); \
    __builtin_amdgcn_sched_barrier(0); \
} while (0)
#define WAIT_LGKM() do { \
    asm volatile("s_waitcnt lgkmcnt(0)" ::: "memory"); \
    __builtin_amdgcn_sched_barrier(0); \
} while (0)
#define WAIT_VM(n) asm volatile("s_waitcnt vmcnt(" #n ")" ::: "memory")

// Stage one 128-row half-tile (2 x global_load_lds per thread).
#define STAGE_A(h, kt, bsel) do { \
    const long kof_ = (long)(kt) * 64; \
    load_lds16(gA0 + (long)((h) * 128) * K_DIM + kof_, \
               lA + (bsel) * 16384 + (h) * 8192); \
    load_lds16(gA0 + (long)((h) * 128 + 64) * K_DIM + kof_, \
               lA + (bsel) * 16384 + (h) * 8192 + 4096); \
} while (0)
#define STAGE_B(h, kt, bsel) do { \
    const long kof_ = (long)(kt) * 64; \
    load_lds16(gB0 + (long)((h) * 128) * K_DIM + kof_, \
               lB + (bsel) * 16384 + (h) * 8192); \
    load_lds16(gB0 + (long)((h) * 128 + 64) * K_DIM + kof_, \
               lB + (bsel) * 16384 + (h) * 8192 + 4096); \
} while (0)

#define READ_A(mh, bsel) do { \
    _Pragma("unroll") \
    for (int mi_ = 0; mi_ < 4; ++mi_) { \
        af[mi_][0] = *(const bf16x8*)(&sA[bsel][baseA0 + ((mh) * 64 + mi_ * 16) * 64]); \
        af[mi_][1] = *(const bf16x8*)(&sA[bsel][baseA1 + ((mh) * 64 + mi_ * 16) * 64]); \
    } \
} while (0)
#define READ_B(nh, bsel) do { \
    _Pragma("unroll") \
    for (int ni_ = 0; ni_ < 2; ++ni_) { \
        bfr[ni_][0] = *(const bf16x8*)(&sB[bsel][baseB0 + ((nh) * 32 + ni_ * 16) * 64]); \
        bfr[ni_][1] = *(const bf16x8*)(&sB[bsel][baseB1 + ((nh) * 32 + ni_ * 16) * 64]); \
    } \
} while (0)

#define DO_MFMA(mh, nh) do { \
    __builtin_amdgcn_s_setprio(1); \
    _Pragma("unroll") \
    for (int mi_ = 0; mi_ < 4; ++mi_) { \
        _Pragma("unroll") \
        for (int ni_ = 0; ni_ < 2; ++ni_) { \
            acc[(mh) * 4 + mi_][(nh) * 2 + ni_] = MFMA16( \
                af[mi_][0], bfr[ni_][0], acc[(mh) * 4 + mi_][(nh) * 2 + ni_], 0, 0, 0); \
            acc[(mh) * 4 + mi_][(nh) * 2 + ni_] = MFMA16( \
                af[mi_][1], bfr[ni_][1], acc[(mh) * 4 + mi_][(nh) * 2 + ni_], 0, 0, 0); \
        } \
    } \
    __builtin_amdgcn_s_setprio(0); \
} while (0)

// One K-tile = 4 phases. sN: stage tile kt+1 halves into buf^1.
// sA2: stage A0(kt+2) into current buf at ph4. vmend: 2 (steady), 0 (drain),
// -1 (skip; last tile).
#define TILE(bsel, kt, sN, sA2, vmend) do { \
    READ_A(0, bsel); READ_B(0, bsel); \
    if (sN) STAGE_A(1, (kt) + 1, (bsel) ^ 1); \
    BAR(); WAIT_LGKM(); DO_MFMA(0, 0); BAR(); \
    READ_B(1, bsel); \
    if (sN) STAGE_B(0, (kt) + 1, (bsel) ^ 1); \
    BAR(); WAIT_LGKM(); DO_MFMA(0, 1); BAR(); \
    READ_A(1, bsel); \
    if (sN) STAGE_B(1, (kt) + 1, (bsel) ^ 1); \
    BAR(); WAIT_LGKM(); DO_MFMA(1, 1); BAR(); \
    READ_B(0, bsel); \
    if (sA2) STAGE_A(0, (kt) + 2, bsel); \
    BAR(); WAIT_LGKM(); DO_MFMA(1, 0); \
    if ((vmend) == 2) { WAIT_VM(2); } \
    else if ((vmend) == 0) { WAIT_VM(0); } \
    BAR(); \
} while (0)

__global__ __launch_bounds__(512, 2) void gemm_bt(
    const unsigned short* __restrict__ A,
    const unsigned short* __restrict__ B,
    float* __restrict__ C)
{
    __shared__ unsigned short sA[2][16384];   // [2 buf][256 rows][64 cols]
    __shared__ unsigned short sB[2][16384];

    const int t    = threadIdx.x;
    const int lane = t & 63;
    const int w    = t >> 6;       // 0..7
    const int wm   = w >> 2;       // 0..1  (M)
    const int wn   = w & 3;        // 0..3  (N)
    const int l16  = lane & 15;
    const int quad = lane >> 4;

    const int m0 = blockIdx.y << 8;
    const int n0 = blockIdx.x << 8;

    // Staging map: thread t -> phys chunks t, t+512 of each half region.
    // phys p: row r=p>>3, logical chunk c=(p&7)^(r&7); +512 and +64-row keep
    // (p&7) and (r&7) unchanged, so one cs serves both loads.
    const int r0 = t >> 3;                                   // 0..63
    const int cs = (((t & 7) ^ ((t >> 3) & 7)) << 3);        // elem offset in row
    const unsigned short* gA0 = A + (long)(m0 + r0) * K_DIM + cs;
    const unsigned short* gB0 = B + (long)(n0 + r0) * K_DIM + cs;
    unsigned short* lA = &sA[0][t * 8];   // +4096 load2, +8192/half, +16384/buf
    unsigned short* lB = &sB[0][t * 8];

    // Fragment LDS bases (elems): row R=(base+l16), phys chunk (ks*4+quad)^(l16&7).
    const int xq = l16 & 7;
    const int baseA0 = ((wm * 128 + l16) << 6) + ((quad ^ xq) << 3);
    const int baseA1 = ((wm * 128 + l16) << 6) + (((4 + quad) ^ xq) << 3);
    const int baseB0 = ((wn * 64 + l16) << 6) + ((quad ^ xq) << 3);
    const int baseB1 = ((wn * 64 + l16) << 6) + (((4 + quad) ^ xq) << 3);

    f32x4 acc[8][4];
#pragma unroll
    for (int i = 0; i < 8; ++i)
#pragma unroll
        for (int j = 0; j < 4; ++j)
            acc[i][j] = (f32x4){0.f, 0.f, 0.f, 0.f};

    bf16x8 af[4][2], bfr[2][2];

    // Prologue: tile0 fully into buf0, plus A0(1) into buf1 (the steady-state
    // ph4-ahead stage). vmcnt(2) => tile0's 8 loads landed; A0(1) may fly.
    STAGE_A(0, 0, 0); STAGE_A(1, 0, 0); STAGE_B(0, 0, 0); STAGE_B(1, 0, 0);
    STAGE_A(0, 1, 1);
    WAIT_VM(2);
    BAR();

    for (int tt = 0; tt < NT / 2 - 1; ++tt) {       // tiles 0..61
        TILE(0, 2 * tt,     1, 1, 2);
        TILE(1, 2 * tt + 1, 1, 1, 2);
    }
    TILE(0, NT - 2, 1, 0, 0);   // stages tile 63 halves; drains vmcnt(0)
    TILE(1, NT - 1, 0, 0, -1);  // no staging, no wait

    // Epilogue: C/D layout col=lane&15, row=quad*4+reg (m89/m91-verified)
#pragma unroll
    for (int mi8 = 0; mi8 < 8; ++mi8) {
#pragma unroll
        for (int ni = 0; ni < 4; ++ni) {
            const int col = n0 + wn * 64 + ni * 16 + l16;
            const long rbase = (long)(m0 + wm * 128 + mi8 * 16 + quad * 4);
#pragma unroll
            for (int r = 0; r < 4; ++r)
                C[(rbase + r) * N_DIM + col] = acc[mi8][ni][r];
        }
    }
}

extern "C" void kernel_launch(void* const* d_in, const int* in_sizes, int n_in,
                              void* d_out, int out_size, void* d_ws, size_t ws_size,
                              hipStream_t stream)
{
    const float* a = (const float*)d_in[0];   // [8][8192][512] fp32
    const float* b = (const float*)d_in[1];   // [8][4096][512] fp32
    float* out = (float*)d_out;               // [8][1024][4096] fp32 == C[8192][4096]

    // Workspace: A_bf16 [8192][4096] (64 MiB) then B_bf16 [4096][4096] (32 MiB)
    unsigned short* Abf = (unsigned short*)d_ws;
    unsigned short* Bbf = Abf + (size_t)M_DIM * K_DIM;

    cvt_fused<<<2048, 256, 0, stream>>>(a, b, Abf, Bbf);

    dim3 grid(N_DIM / 256, M_DIM / 256);      // 16 x 32 = 512 blocks
    gemm_bt<<<grid, 512, 0, stream>>>(Abf, Bbf, out);
}

// Round 5
// 497.689 us; speedup vs baseline: 1.3023x; 1.0609x over previous
//
#include <hip/hip_runtime.h>
#include <hip/hip_bf16.h>
#include <stdint.h>

// Problem constants (fixed by the reference)
#define NUM_RANKS 8
#define M_DIM 8192   // global token dim
#define N_DIM 4096   // output features
#define K_LOC 512    // per-rank K shard
#define K_DIM 4096   // NUM_RANKS * K_LOC — effective GEMM K
#define NT    (K_DIM / 64)   // 64 K-tiles of BK=64

typedef __bf16 bf16x8 __attribute__((ext_vector_type(8)));
typedef float f32x4 __attribute__((ext_vector_type(4)));

// RNE float->bf16 (inputs are finite gaussians)
__device__ __forceinline__ uint32_t f2bf(float f) {
    union { float f; uint32_t u; } cv;
    cv.f = f;
    uint32_t x = cv.u;
    return ((x + 0x7fffu + ((x >> 16) & 1u)) >> 16) & 0xffffu;
}

// Fused convert + relayout (R3-passing version, unchanged).
//   a[src][row][k] fp32 -> Abf[row][src*512+k] bf16   (rowShift=13)
//   b[src][row][k] fp32 -> Bbf[row][src*512+k] bf16   (rowShift=12)
__global__ __launch_bounds__(256) void cvt_fused(
    const float* __restrict__ a, const float* __restrict__ b,
    unsigned short* __restrict__ Abf, unsigned short* __restrict__ Bbf)
{
    const long ACH = (long)NUM_RANKS * M_DIM * (K_LOC / 8);          // 4194304 chunks
    const long TCH = ACH + (long)NUM_RANKS * N_DIM * (K_LOC / 8);    // +2097152
    for (long c = (long)blockIdx.x * 256 + threadIdx.x; c < TCH;
         c += (long)gridDim.x * 256) {
        const float* in; unsigned short* out; long e; int rowShift;
        if (c < ACH) { in = a; out = Abf; e = c << 3;        rowShift = 13; }
        else         { in = b; out = Bbf; e = (c - ACH) << 3; rowShift = 12; }
        const int src = (int)(e >> (rowShift + 9));
        const int row = (int)((e >> 9) & ((1 << rowShift) - 1));
        const int k   = (int)(e & 511);
        const float4 f0 = *(const float4*)(in + e);
        const float4 f1 = *(const float4*)(in + e + 4);
        uint4 v;
        v.x = f2bf(f0.x) | (f2bf(f0.y) << 16);
        v.y = f2bf(f0.z) | (f2bf(f0.w) << 16);
        v.z = f2bf(f1.x) | (f2bf(f1.y) << 16);
        v.w = f2bf(f1.z) | (f2bf(f1.w) << 16);
        *(uint4*)(out + ((long)row << 12) + (src << 9) + k) = v;
    }
}

// 16B direct global->LDS DMA. LDS dst: wave-uniform base + lane*16.
// Global src per-lane => swizzle realized by inverse-swizzling the SOURCE
// column; LDS stays linear (both-sides-or-neither rule).
__device__ __forceinline__ void load_lds16(const void* g, void* l) {
    __builtin_amdgcn_global_load_lds(
        (__attribute__((address_space(1))) void*)g,
        (__attribute__((address_space(3))) void*)l,
        16, 0, 0);
}

// ============================================================================
// 256x256 pipelined-read GEMM (R5), C[M][N] = A[M][K]*B[N][K]^T, bf16->fp32.
// 512 thr = 8 waves (2M x 4N), per-wave 128x64 out, BK=64, 128 KiB LDS dbuf.
//
// HALF-OWNERSHIP MAP (the R4 bug): stage-half h covers rows h*128..h*128+127.
// A-fragment reads: wm=0 waves ALWAYS read h0, wm=1 ALWAYS h1 (both mh).
// B-fragment reads: wn in {0,1} ALWAYS h0, wn in {2,3} ALWAYS h1 (both nh).
// => any early read of tile t+1 frags needs ALL FOUR halves of t+1 confirmed.
// R4's VM_2@ph3 left B1h(t+1) (staged ph3) unconfirmed -> wn 2,3 read stale.
//
// Stage schedule per tile t (buf b = t&1), fixing that:
//   ph1: A1h(t+1) -> b^1                       [2 loads]
//   ph3: B0h(t+2) -> b   (issued before VM)    [2 loads]
//   ph4: A0h(t+2) -> b,  B1h(t+2) -> b         [4 loads]
// In-flight at ph3(t) (oldest first): B0h(t+1), A0h(t+1), B1h(t+1) [t-1's
// ph3/ph4], A1h(t+1) [ph1], + B0h(t+2) just issued = 10. vmcnt(2) confirms
// the first 8 = ALL of tile t+1; leaves B0h(t+2) in flight (counted, never 0
// in steady state). Single VM wait per tile.
//
// Restage safety (confirm-then-barrier before any wave's stage issue):
//   A1h(b^1)@ph1(t): last reads conf LGKM(4)@ph1(t-1) [early rd] and
//     LGKM(0)@ph3(t-1) [ph2 rd]; barriers ph3/ph4(t-1). OK
//   B0h(b)@ph3(t): conf LGKM(4)@ph1(t) [early rd] and LGKM(8)@ph2(t)
//     [ph1 rd]; barrier end-ph2. OK
//   A0h(b)@ph4(t): conf LGKM(4)@ph1(t) and LGKM(0)@ph3(t); barrier end-ph3.
//     (ph3 placement would race wm=0's ph2 read of rows 64..127 -> ph4.)
//   B1h(b)@ph4(t): conf LGKM(8)@ph2(t) and LGKM(4)@ph1(t); barriers. OK
//
// Reads/phase (issue N+1's frags while MFMA N runs; counted lgkm):
//   ph1: B1(4 rds)  LGKM(4)->A0,B0 ok   MFMA(0,0)
//   ph2: A1(8 rds)  LGKM(8)->B1 ok      MFMA(0,1)
//   ph3: none       LGKM(0)->A1 ok      MFMA(1,1)
//   ph4: A0,B0 of t+1 (12 rds, no wait) MFMA(1,0) [reads regs conf'd earlier]
// Counts robust to b128 splitting (older-than barrier => oldest in queue).
//
// All barriers/waits: asm + "memory" clobber + sched_barrier(0) (rule #18).
// ============================================================================

#define MFMA16 __builtin_amdgcn_mfma_f32_16x16x32_bf16
#define BAR() do { \
    __builtin_amdgcn_sched_barrier(0); \
    asm volatile("s_barrier" ::: "memory"); \
    __builtin_amdgcn_sched_barrier(0); \
} while (0)
#define LGKM(n) do { \
    asm volatile("s_waitcnt lgkmcnt(" #n ")" ::: "memory"); \
    __builtin_amdgcn_sched_barrier(0); \
} while (0)
#define VM_6    asm volatile("s_waitcnt vmcnt(6)" ::: "memory")
#define VM_2    asm volatile("s_waitcnt vmcnt(2)" ::: "memory")
#define VM_0    asm volatile("s_waitcnt vmcnt(0)" ::: "memory")
#define VM_NONE

// Stage one 128-row half-tile (2 x global_load_lds per thread).
#define STAGE_A(h, kt, bsel) do { \
    const long kof_ = (long)(kt) * 64; \
    load_lds16(gA0 + (long)((h) * 128) * K_DIM + kof_, \
               lA + (bsel) * 16384 + (h) * 8192); \
    load_lds16(gA0 + (long)((h) * 128 + 64) * K_DIM + kof_, \
               lA + (bsel) * 16384 + (h) * 8192 + 4096); \
} while (0)
#define STAGE_B(h, kt, bsel) do { \
    const long kof_ = (long)(kt) * 64; \
    load_lds16(gB0 + (long)((h) * 128) * K_DIM + kof_, \
               lB + (bsel) * 16384 + (h) * 8192); \
    load_lds16(gB0 + (long)((h) * 128 + 64) * K_DIM + kof_, \
               lB + (bsel) * 16384 + (h) * 8192 + 4096); \
} while (0)

// Fragment reads: dst is a LITERAL register-set index (static indexing).
#define RD_A(mh, dst, bsel) do { \
    _Pragma("unroll") \
    for (int mi_ = 0; mi_ < 4; ++mi_) { \
        af[dst][mi_][0] = *(const bf16x8*)(&sA[bsel][baseA0 + ((mh) * 64 + mi_ * 16) * 64]); \
        af[dst][mi_][1] = *(const bf16x8*)(&sA[bsel][baseA1 + ((mh) * 64 + mi_ * 16) * 64]); \
    } \
} while (0)
#define RD_B(nh, dst, bsel) do { \
    _Pragma("unroll") \
    for (int ni_ = 0; ni_ < 2; ++ni_) { \
        bq[dst][ni_][0] = *(const bf16x8*)(&sB[bsel][baseB0 + ((nh) * 32 + ni_ * 16) * 64]); \
        bq[dst][ni_][1] = *(const bf16x8*)(&sB[bsel][baseB1 + ((nh) * 32 + ni_ * 16) * 64]); \
    } \
} while (0)

#define DO_MFMA(mh, nh, aset, bset) do { \
    __builtin_amdgcn_s_setprio(1); \
    _Pragma("unroll") \
    for (int mi_ = 0; mi_ < 4; ++mi_) { \
        _Pragma("unroll") \
        for (int ni_ = 0; ni_ < 2; ++ni_) { \
            acc[(mh) * 4 + mi_][(nh) * 2 + ni_] = MFMA16( \
                af[aset][mi_][0], bq[bset][ni_][0], \
                acc[(mh) * 4 + mi_][(nh) * 2 + ni_], 0, 0, 0); \
            acc[(mh) * 4 + mi_][(nh) * 2 + ni_] = MFMA16( \
                af[aset][mi_][1], bq[bset][ni_][1], \
                acc[(mh) * 4 + mi_][(nh) * 2 + ni_], 0, 0, 0); \
        } \
    } \
    __builtin_amdgcn_s_setprio(0); \
} while (0)

// One K-tile = 4 phases, 1 barrier each. Entering ph1: af0+bq[bsel] (12 reads)
// issued last ph4; ALL of tile kt's LDS halves vm-confirmed.
#define TILE(bsel, kt, sP1, sP3, sP4, e1, VMA) do { \
    /* ph1: MFMA(0,0)=af0 x B0 */ \
    RD_B(1, 2, bsel); \
    if (sP1) STAGE_A(1, (kt) + 1, (bsel) ^ 1); \
    LGKM(4);  DO_MFMA(0, 0, 0, bsel);  BAR(); \
    /* ph2: MFMA(0,1)=af0 x B1 */ \
    RD_A(1, 1, bsel); \
    LGKM(8);  DO_MFMA(0, 1, 0, 2);     BAR(); \
    /* ph3: MFMA(1,1)=af1 x B1; stage B0h(kt+2) then counted VM */ \
    if (sP3) STAGE_B(0, (kt) + 2, bsel); \
    LGKM(0);  DO_MFMA(1, 1, 1, 2); \
    VMA;  BAR(); \
    /* ph4: MFMA(1,0)=af1 x B0; early-issue tile kt+1 ph1 frags */ \
    if (e1) { RD_A(0, 0, (bsel) ^ 1); RD_B(0, (bsel) ^ 1, (bsel) ^ 1); } \
    if (sP4) { STAGE_A(0, (kt) + 2, bsel); STAGE_B(1, (kt) + 2, bsel); } \
    DO_MFMA(1, 0, 1, bsel); \
    BAR(); \
} while (0)

__global__ __launch_bounds__(512, 2) void gemm_bt(
    const unsigned short* __restrict__ A,
    const unsigned short* __restrict__ B,
    float* __restrict__ C)
{
    __shared__ unsigned short sA[2][16384];   // [2 buf][256 rows][64 cols]
    __shared__ unsigned short sB[2][16384];

    const int t    = threadIdx.x;
    const int lane = t & 63;
    const int w    = t >> 6;       // 0..7
    const int wm   = w >> 2;       // 0..1  (M)
    const int wn   = w & 3;        // 0..3  (N)
    const int l16  = lane & 15;
    const int quad = lane >> 4;

    const int m0 = blockIdx.y << 8;
    const int n0 = blockIdx.x << 8;

    // Staging map: thread t -> phys chunks t, t+512 of each half region.
    // phys p: row r=p>>3, logical chunk c=(p&7)^(r&7); one cs serves both.
    const int r0 = t >> 3;                                   // 0..63
    const int cs = (((t & 7) ^ ((t >> 3) & 7)) << 3);        // elem offset in row
    const unsigned short* gA0 = A + (long)(m0 + r0) * K_DIM + cs;
    const unsigned short* gB0 = B + (long)(n0 + r0) * K_DIM + cs;
    unsigned short* lA = &sA[0][t * 8];   // +4096 load2, +8192/half, +16384/buf
    unsigned short* lB = &sB[0][t * 8];

    // Fragment LDS bases (elems): row base+l16, phys chunk (ks*4+quad)^(l16&7).
    const int xq = l16 & 7;
    const int baseA0 = ((wm * 128 + l16) << 6) + ((quad ^ xq) << 3);
    const int baseA1 = ((wm * 128 + l16) << 6) + (((4 + quad) ^ xq) << 3);
    const int baseB0 = ((wn * 64 + l16) << 6) + ((quad ^ xq) << 3);
    const int baseB1 = ((wn * 64 + l16) << 6) + (((4 + quad) ^ xq) << 3);

    f32x4 acc[8][4];
#pragma unroll
    for (int i = 0; i < 8; ++i)
#pragma unroll
        for (int j = 0; j < 4; ++j)
            acc[i][j] = (f32x4){0.f, 0.f, 0.f, 0.f};

    // Register fragment buffers — ALL indices compile-time literals (rule #20).
    bf16x8 af[2][4][2];   // af[0]=mh0 rows, af[1]=mh1 rows (x4 mtiles x2 khalves)
    bf16x8 bq[3][2][2];   // bq[t&1]=B0(t), bq[2]=B1(t)

    // Prologue: tile0 (8 loads -> buf0), then B0h(1), A0h(1), B1h(1) -> buf1
    // in the steady-state queue order. vmcnt(6) confirms tile0's 8; the 6
    // tile-1 loads stay in flight. Then issue tile0's ph1 frag reads.
    STAGE_A(0, 0, 0); STAGE_A(1, 0, 0); STAGE_B(0, 0, 0); STAGE_B(1, 0, 0);
    STAGE_B(0, 1, 1); STAGE_A(0, 1, 1); STAGE_B(1, 1, 1);
    VM_6;
    BAR();
    RD_A(0, 0, 0); RD_B(0, 0, 0);

    for (int tt = 0; tt < NT / 2 - 1; ++tt) {       // tiles 0..61
        TILE(0, 2 * tt,     1, 1, 1, 1, VM_2);
        TILE(1, 2 * tt + 1, 1, 1, 1, 1, VM_2);
    }
    TILE(0, NT - 2, 1, 0, 0, 1, VM_0);   // stages A1h(63) only; drains all
    TILE(1, NT - 1, 0, 0, 0, 0, VM_NONE);

    // Epilogue: C/D layout col=lane&15, row=quad*4+reg (m89/m91-verified)
#pragma unroll
    for (int mi8 = 0; mi8 < 8; ++mi8) {
#pragma unroll
        for (int ni = 0; ni < 4; ++ni) {
            const int col = n0 + wn * 64 + ni * 16 + l16;
            const long rbase = (long)(m0 + wm * 128 + mi8 * 16 + quad * 4);
#pragma unroll
            for (int r = 0; r < 4; ++r)
                C[(rbase + r) * N_DIM + col] = acc[mi8][ni][r];
        }
    }
}

extern "C" void kernel_launch(void* const* d_in, const int* in_sizes, int n_in,
                              void* d_out, int out_size, void* d_ws, size_t ws_size,
                              hipStream_t stream)
{
    const float* a = (const float*)d_in[0];   // [8][8192][512] fp32
    const float* b = (const float*)d_in[1];   // [8][4096][512] fp32
    float* out = (float*)d_out;               // [8][1024][4096] fp32 == C[8192][4096]

    // Workspace: A_bf16 [8192][4096] (64 MiB) then B_bf16 [4096][4096] (32 MiB)
    unsigned short* Abf = (unsigned short*)d_ws;
    unsigned short* Bbf = Abf + (size_t)M_DIM * K_DIM;

    cvt_fused<<<2048, 256, 0, stream>>>(a, b, Abf, Bbf);

    dim3 grid(N_DIM / 256, M_DIM / 256);      // 16 x 32 = 512 blocks
    gemm_bt<<<grid, 512, 0, stream>>>(Abf, Bbf, out);
}